// Round 5
// baseline (4000.040 us; speedup 1.0000x reference)
//
#include <hip/hip_runtime.h>

#define HID 16
#define OUTC 4
#define G 128            // nodes per bucket
#define GSH 7            // log2(G)
#define SLOTS 16         // sub-cursors per bucket (contention spreading)
#define SPLIT 4          // blocks per bucket in aggregation

__device__ __forceinline__ float relu(float v) { return v > 0.f ? v : 0.f; }

// ---- per-node degree + per-(bucket,slot) histogram, one pass over dst ----
__global__ void k_deg2(const int* __restrict__ dst, int* __restrict__ deg,
                       int* __restrict__ hist2, int E) {
    for (int i = blockIdx.x * blockDim.x + threadIdx.x; i < E; i += gridDim.x * blockDim.x) {
        int d = dst[i];
        atomicAdd(deg + d, 1);
        atomicAdd(hist2 + ((d >> GSH) * SLOTS + ((i >> 6) & (SLOTS - 1))), 1);
    }
}

__global__ void k_dinv(const int* __restrict__ deg, float* __restrict__ dinv, int N) {
    int i = blockIdx.x * blockDim.x + threadIdx.x;
    if (i < N) dinv[i] = rsqrtf((float)deg[i] + 1.0f);   // +1 self-loop; deg>0 always
}

// ---- single-block exclusive scan of 25008 bins -> cursor, bOff ----
__global__ void k_scan(const int* __restrict__ hist2, int* __restrict__ cursor,
                       int* __restrict__ bOff, int bins, int nb, int E) {
    __shared__ int s[1024];
    int carry = 0;
    for (int base = 0; base < bins; base += 1024) {
        int idx = base + threadIdx.x;
        int v = (idx < bins) ? hist2[idx] : 0;
        s[threadIdx.x] = v; __syncthreads();
        for (int off = 1; off < 1024; off <<= 1) {
            int t = (threadIdx.x >= (unsigned)off) ? s[threadIdx.x - off] : 0;
            __syncthreads();
            s[threadIdx.x] += t;
            __syncthreads();
        }
        if (idx < bins) {
            int ex = carry + s[threadIdx.x] - v;
            cursor[idx] = ex;
            if ((idx & (SLOTS - 1)) == 0) bOff[idx / SLOTS] = ex;
        }
        carry += s[1023];
        __syncthreads();
    }
    if (threadIdx.x == 0) bOff[nb] = E;
}

// ---- partition edges into bucket regions (16 low-contention streams per bucket) ----
__global__ void k_part(const int* __restrict__ src, const int* __restrict__ dst,
                       int* __restrict__ cursor, unsigned int* __restrict__ rec, int E) {
    for (int i = blockIdx.x * blockDim.x + threadIdx.x; i < E; i += gridDim.x * blockDim.x) {
        int s = src[i], d = dst[i];
        int bin = (d >> GSH) * SLOTS + ((i >> 6) & (SLOTS - 1));
        int p = atomicAdd(cursor + bin, 1);
        rec[p] = (unsigned int)s | ((unsigned int)(d & (G - 1)) << 18);
    }
}

// ---- mS1[n][c] = x[n] * W1[c] * dinv[n]  (IN_C == 1) ----
__global__ void k_m1(const float* __restrict__ x, const float* __restrict__ W1,
                     const float* __restrict__ dinv, float* __restrict__ m, int N) {
    int t = blockIdx.x * blockDim.x + threadIdx.x;
    if (t < N * HID) {
        int n = t >> 4, c = t & 15;
        m[t] = x[n] * W1[c] * dinv[n];
    }
}

// ---- in-place h -> (h @ W2) * dinv, 64 nodes per 256-thread block via LDS ----
__global__ void k_m2(float4* __restrict__ h4, const float* __restrict__ W2,
                     const float* __restrict__ dinv, int N) {
    __shared__ float hs[64][HID + 1];
    __shared__ float w[HID * HID];
    if (threadIdx.x < HID * HID) w[threadIdx.x] = W2[threadIdx.x];
    int idx = blockIdx.x * 256 + threadIdx.x;          // float4 index
    int n = idx >> 2, q = idx & 3;
    int ln = threadIdx.x >> 2;
    if (n < N) {
        float4 v = h4[idx];
        hs[ln][q * 4 + 0] = v.x; hs[ln][q * 4 + 1] = v.y;
        hs[ln][q * 4 + 2] = v.z; hs[ln][q * 4 + 3] = v.w;
    }
    __syncthreads();
    if (n < N) {
        float dn = dinv[n];
        float4 acc = make_float4(0.f, 0.f, 0.f, 0.f);
        const float* hr = hs[ln];
#pragma unroll
        for (int ci = 0; ci < HID; ++ci) {
            float hv = hr[ci];
            const float* wr = w + ci * HID + q * 4;
            acc.x += hv * wr[0]; acc.y += hv * wr[1];
            acc.z += hv * wr[2]; acc.w += hv * wr[3];
        }
        acc.x *= dn; acc.y *= dn; acc.z *= dn; acc.w *= dn;
        h4[idx] = acc;
    }
}

// ---- bucket aggregation: SPLIT blocks per bucket, LDS partial, atomic merge ----
__global__ void __launch_bounds__(256, 8)
k_agg(const int* __restrict__ bOff, const unsigned int* __restrict__ rec,
      const float4* __restrict__ mS4, float* __restrict__ gagg, int N) {
    __shared__ float agg[G * 17];
    int b = blockIdx.x / SPLIT, sp = blockIdx.x % SPLIT;
    int beg = bOff[b], end = bOff[b + 1];
    int chunk = (end - beg + SPLIT - 1) / SPLIT;
    int lo = beg + sp * chunk;
    int hi = lo + chunk < end ? lo + chunk : end;
    for (int i = threadIdx.x; i < G * 17; i += 256) agg[i] = 0.f;
    __syncthreads();
    int q = threadIdx.x & 3;
    for (int i = lo + (threadIdx.x >> 2); i < hi; i += 64) {
        unsigned int r = rec[i];
        int s = r & 0x3FFFF;
        int dl = r >> 18;
        float4 mv = mS4[s * 4 + q];
        float* a = agg + dl * 17 + q * 4;
        atomicAdd(a + 0, mv.x); atomicAdd(a + 1, mv.y);
        atomicAdd(a + 2, mv.z); atomicAdd(a + 3, mv.w);
    }
    __syncthreads();
    int base = b * G;
    for (int v = threadIdx.x; v < G * HID; v += 256) {
        int nl = v >> 4, c = v & 15;
        int n = base + nl;
        if (n >= N) break;
        float val = agg[nl * 17 + c];
        if (val != 0.f) atomicAdd(gagg + n * HID + c, val);
    }
}

// ---- epilogue layer1: h = relu((gagg + mS[n]) * dinv[n] + b) ----
__global__ void k_post(const float4* __restrict__ gagg4, const float4* __restrict__ mS4,
                       const float* __restrict__ dinv, const float4* __restrict__ b4,
                       float4* __restrict__ h4, int N) {
    int t = blockIdx.x * blockDim.x + threadIdx.x;
    if (t < N * 4) {
        int n = t >> 2, q = t & 3;
        float dn = dinv[n];
        float4 ag = gagg4[t];
        float4 ms = mS4[t];
        float4 bb = b4[q];
        float4 hv;
        hv.x = relu((ag.x + ms.x) * dn + bb.x);
        hv.y = relu((ag.y + ms.y) * dn + bb.y);
        hv.z = relu((ag.z + ms.z) * dn + bb.z);
        hv.w = relu((ag.w + ms.w) * dn + bb.w);
        h4[t] = hv;
    }
}

// ---- epilogue layer2 + readout: out = relu((gagg+mS)*dinv + b2) @ Wl + bl ----
__global__ void k_out(const float4* __restrict__ gagg4, const float4* __restrict__ mS4,
                      const float* __restrict__ dinv, const float4* __restrict__ b4,
                      const float* __restrict__ Wl, const float* __restrict__ bl,
                      float* __restrict__ out, int N) {
    __shared__ float hs[64][HID + 1];
    __shared__ float wl[HID * OUTC];
    __shared__ float blv[OUTC];
    if (threadIdx.x < HID * OUTC) wl[threadIdx.x] = Wl[threadIdx.x];
    if (threadIdx.x < OUTC) blv[threadIdx.x] = bl[threadIdx.x];
    int idx = blockIdx.x * 256 + threadIdx.x;          // float4 index
    int n = idx >> 2, q = idx & 3;
    int ln = threadIdx.x >> 2;
    if (n < N) {
        float dn = dinv[n];
        float4 ag = gagg4[idx];
        float4 ms = mS4[idx];
        float4 bb = b4[q];
        hs[ln][q * 4 + 0] = relu((ag.x + ms.x) * dn + bb.x);
        hs[ln][q * 4 + 1] = relu((ag.y + ms.y) * dn + bb.y);
        hs[ln][q * 4 + 2] = relu((ag.z + ms.z) * dn + bb.z);
        hs[ln][q * 4 + 3] = relu((ag.w + ms.w) * dn + bb.w);
    }
    __syncthreads();
    if (n < N) {   // thread -> (node ln, out-channel q)
        float acc = blv[q];
        const float* hr = hs[ln];
#pragma unroll
        for (int ci = 0; ci < HID; ++ci) acc += hr[ci] * wl[ci * OUTC + q];
        out[n * OUTC + q] = acc;
    }
}

// ---------- launch ----------
static inline size_t alignup(size_t v, size_t a) { return (v + a - 1) & ~(a - 1); }

extern "C" void kernel_launch(void* const* d_in, const int* in_sizes, int n_in,
                              void* d_out, int out_size, void* d_ws, size_t ws_size,
                              hipStream_t stream) {
    const float* x  = (const float*)d_in[0];
    const int* ed   = (const int*)d_in[1];     // int inputs delivered as int32
    const float* W1 = (const float*)d_in[2];
    const float* b1 = (const float*)d_in[3];
    const float* W2 = (const float*)d_in[4];
    const float* b2 = (const float*)d_in[5];
    const float* Wl = (const float*)d_in[6];
    const float* bl = (const float*)d_in[7];
    float* out      = (float*)d_out;

    int N = in_sizes[0];
    int E = in_sizes[1] / 2;
    const int* src = ed;
    const int* dst = ed + E;
    int nb = (N + G - 1) / G;
    int bins = nb * SLOTS;

    // workspace
    char* w = (char*)d_ws;
    size_t o = 0;
    int* deg          = (int*)(w + o); o = alignup(o + (size_t)N * 4, 16);
    int* hist2        = (int*)(w + o); o = alignup(o + (size_t)bins * 4, 16);
    int* cursor       = (int*)(w + o); o = alignup(o + (size_t)bins * 4, 16);
    int* bOff         = (int*)(w + o); o = alignup(o + ((size_t)nb + 1) * 4, 16);
    float* dinv       = (float*)(w + o); o = alignup(o + (size_t)N * 4, 16);
    unsigned int* rec = (unsigned int*)(w + o); o = alignup(o + (size_t)E * 4, 16);
    float* bufA       = (float*)(w + o); o = alignup(o + (size_t)N * HID * 4, 16);  // mS / h (in place)
    float* bufB       = (float*)(w + o); o = alignup(o + (size_t)N * HID * 4, 16);  // gagg
    (void)ws_size;

    int blk = 256;
    int gN16 = (N * HID + blk - 1) / blk;
    int gN4  = (N * 4 + blk - 1) / blk;
    int gNode64 = (N + 63) / 64;

    // build dinv + partitioned records
    hipMemsetAsync(deg, 0, (size_t)N * 4, stream);
    hipMemsetAsync(hist2, 0, (size_t)bins * 4, stream);
    k_deg2<<<4096, blk, 0, stream>>>(dst, deg, hist2, E);
    k_dinv<<<(N + blk - 1) / blk, blk, 0, stream>>>(deg, dinv, N);
    k_scan<<<1, 1024, 0, stream>>>(hist2, cursor, bOff, bins, nb, E);
    k_part<<<4096, blk, 0, stream>>>(src, dst, cursor, rec, E);

    // layer 1
    k_m1<<<gN16, blk, 0, stream>>>(x, W1, dinv, bufA, N);
    hipMemsetAsync(bufB, 0, (size_t)N * HID * 4, stream);
    k_agg<<<nb * SPLIT, blk, 0, stream>>>(bOff, rec, (const float4*)bufA, bufB, N);
    k_post<<<gN4, blk, 0, stream>>>((const float4*)bufB, (const float4*)bufA, dinv,
                                    (const float4*)b1, (float4*)bufA, N);   // bufA = h1

    // layer 2
    k_m2<<<gNode64, blk, 0, stream>>>((float4*)bufA, W2, dinv, N);          // bufA = mS2 (in place)
    hipMemsetAsync(bufB, 0, (size_t)N * HID * 4, stream);
    k_agg<<<nb * SPLIT, blk, 0, stream>>>(bOff, rec, (const float4*)bufA, bufB, N);
    k_out<<<gNode64, blk, 0, stream>>>((const float4*)bufB, (const float4*)bufA, dinv,
                                       (const float4*)b2, Wl, bl, out, N);
}

// Round 6
// 2352.776 us; speedup vs baseline: 1.7001x; 1.7001x over previous
//
#include <hip/hip_runtime.h>

#define HID 16
#define OUTC 4
#define G 128            // nodes per bucket
#define GSH 7            // log2(G)
#define SPLIT 4          // blocks per bucket in aggregation
#define CHUNKS 1024      // edge chunks for partition passes
#define PBLK 512         // threads per partition-pass block
#define MAXNB 2048       // max buckets supported by LDS tables

__device__ __forceinline__ float relu(float v) { return v > 0.f ? v : 0.f; }

// ---- Pass A: per-(bucket,chunk) counts via LDS histogram (no global atomics) ----
__global__ void k_cnt(const int* __restrict__ dst, int* __restrict__ cnt, int E, int nb) {
    __shared__ int lc[MAXNB];
    for (int i = threadIdx.x; i < nb; i += PBLK) lc[i] = 0;
    __syncthreads();
    int c = blockIdx.x;
    int chunk = (E + CHUNKS - 1) / CHUNKS;
    int lo = c * chunk, hi = lo + chunk < E ? lo + chunk : E;
    for (int i = lo + threadIdx.x; i < hi; i += PBLK)
        atomicAdd(lc + (dst[i] >> GSH), 1);
    __syncthreads();
    for (int b = threadIdx.x; b < nb; b += PBLK)
        cnt[b * CHUNKS + c] = lc[b];
}

// ---- hierarchical exclusive scan over cnt[nb*CHUNKS] ----
__global__ void k_scanA(int* __restrict__ a, int* __restrict__ bsum, int L) {
    __shared__ int s[1024];
    int i = blockIdx.x * 1024 + threadIdx.x;
    int v = (i < L) ? a[i] : 0;
    s[threadIdx.x] = v; __syncthreads();
    for (int off = 1; off < 1024; off <<= 1) {
        int t = (threadIdx.x >= (unsigned)off) ? s[threadIdx.x - off] : 0;
        __syncthreads();
        s[threadIdx.x] += t;
        __syncthreads();
    }
    if (i < L) a[i] = s[threadIdx.x] - v;               // block-local exclusive
    if (threadIdx.x == 1023) bsum[blockIdx.x] = s[1023];
}

__global__ void k_scanB(int* __restrict__ bsum, int SB) {
    __shared__ int s[1024];
    int carry = 0;
    for (int base = 0; base < SB; base += 1024) {
        int idx = base + threadIdx.x;
        int v = (idx < SB) ? bsum[idx] : 0;
        s[threadIdx.x] = v; __syncthreads();
        for (int off = 1; off < 1024; off <<= 1) {
            int t = (threadIdx.x >= (unsigned)off) ? s[threadIdx.x - off] : 0;
            __syncthreads();
            s[threadIdx.x] += t;
            __syncthreads();
        }
        if (idx < SB) bsum[idx] = carry + s[threadIdx.x] - v;   // exclusive
        carry += s[1023];
        __syncthreads();
    }
}

__global__ void k_scanC(int* __restrict__ a, const int* __restrict__ bsum,
                        int* __restrict__ bOff, int L, int nb, int E) {
    int i = blockIdx.x * 1024 + threadIdx.x;
    if (i < L) {
        int v = a[i] + bsum[blockIdx.x];
        a[i] = v;
        if ((i & (CHUNKS - 1)) == 0) bOff[i / CHUNKS] = v;  // CHUNKS==1024==scan width
    }
    if (i == 0) bOff[nb] = E;
}

// ---- Pass B: partition writes with exact offsets (LDS cursors, no global atomics) ----
__global__ void k_part(const int* __restrict__ src, const int* __restrict__ dst,
                       const int* __restrict__ cnt, unsigned int* __restrict__ rec,
                       int E, int nb) {
    __shared__ int cur[MAXNB];
    int c = blockIdx.x;
    for (int b = threadIdx.x; b < nb; b += PBLK) cur[b] = cnt[b * CHUNKS + c];
    __syncthreads();
    int chunk = (E + CHUNKS - 1) / CHUNKS;
    int lo = c * chunk, hi = lo + chunk < E ? lo + chunk : E;
    for (int i = lo + threadIdx.x; i < hi; i += PBLK) {
        int d = dst[i], s = src[i];
        int p = atomicAdd(cur + (d >> GSH), 1);         // LDS atomic
        rec[p] = (unsigned int)s | ((unsigned int)(d & (G - 1)) << 18);
    }
}

// ---- per-node degree from bucket records -> dinv ----
__global__ void k_degb(const int* __restrict__ bOff, const unsigned int* __restrict__ rec,
                       float* __restrict__ dinv, int N) {
    __shared__ int cnt[G];
    int b = blockIdx.x;
    if (threadIdx.x < G) cnt[threadIdx.x] = 0;
    __syncthreads();
    int beg = bOff[b], end = bOff[b + 1];
    for (int i = beg + threadIdx.x; i < end; i += 256)
        atomicAdd(cnt + (rec[i] >> 18), 1);             // LDS atomic
    __syncthreads();
    int n = b * G + threadIdx.x;
    if (threadIdx.x < G && n < N)
        dinv[n] = rsqrtf((float)cnt[threadIdx.x] + 1.0f);   // +1 self-loop
}

// ---- mS1[n][c] = x[n] * W1[c] * dinv[n]  (IN_C == 1) ----
__global__ void k_m1(const float* __restrict__ x, const float* __restrict__ W1,
                     const float* __restrict__ dinv, float* __restrict__ m, int N) {
    int t = blockIdx.x * blockDim.x + threadIdx.x;
    if (t < N * HID) {
        int n = t >> 4, c = t & 15;
        m[t] = x[n] * W1[c] * dinv[n];
    }
}

// ---- in-place h -> (h @ W2) * dinv ----
__global__ void k_m2(float4* __restrict__ h4, const float* __restrict__ W2,
                     const float* __restrict__ dinv, int N) {
    __shared__ float hs[64][HID + 1];
    __shared__ float w[HID * HID];
    if (threadIdx.x < HID * HID) w[threadIdx.x] = W2[threadIdx.x];
    int idx = blockIdx.x * 256 + threadIdx.x;          // float4 index
    int n = idx >> 2, q = idx & 3;
    int ln = threadIdx.x >> 2;
    if (n < N) {
        float4 v = h4[idx];
        hs[ln][q * 4 + 0] = v.x; hs[ln][q * 4 + 1] = v.y;
        hs[ln][q * 4 + 2] = v.z; hs[ln][q * 4 + 3] = v.w;
    }
    __syncthreads();
    if (n < N) {
        float dn = dinv[n];
        float4 acc = make_float4(0.f, 0.f, 0.f, 0.f);
        const float* hr = hs[ln];
#pragma unroll
        for (int ci = 0; ci < HID; ++ci) {
            float hv = hr[ci];
            const float* wr = w + ci * HID + q * 4;
            acc.x += hv * wr[0]; acc.y += hv * wr[1];
            acc.z += hv * wr[2]; acc.w += hv * wr[3];
        }
        acc.x *= dn; acc.y *= dn; acc.z *= dn; acc.w *= dn;
        h4[idx] = acc;
    }
}

// ---- bucket aggregation: SPLIT blocks/bucket, 4-way ILP, LDS accumulate, coalesced merge ----
__global__ void __launch_bounds__(256, 6)
k_agg(const int* __restrict__ bOff, const unsigned int* __restrict__ rec,
      const float4* __restrict__ mS4, float* __restrict__ gagg, int N) {
    __shared__ float agg[G * 17];
    int b = blockIdx.x / SPLIT, sp = blockIdx.x % SPLIT;
    int beg = bOff[b], end = bOff[b + 1];
    int chunk = (end - beg + SPLIT - 1) / SPLIT;
    int lo = beg + sp * chunk;
    int hi = lo + chunk < end ? lo + chunk : end;
    for (int i = threadIdx.x; i < G * 17; i += 256) agg[i] = 0.f;
    __syncthreads();
    int q = threadIdx.x & 3;
    int gid = threadIdx.x >> 2;
    int i = lo + gid;
    for (; i + 192 < hi; i += 256) {                    // 4 gathers in flight
        unsigned int r0 = rec[i], r1 = rec[i + 64], r2 = rec[i + 128], r3 = rec[i + 192];
        float4 m0 = mS4[(r0 & 0x3FFFF) * 4 + q];
        float4 m1 = mS4[(r1 & 0x3FFFF) * 4 + q];
        float4 m2 = mS4[(r2 & 0x3FFFF) * 4 + q];
        float4 m3 = mS4[(r3 & 0x3FFFF) * 4 + q];
        float* a0 = agg + (r0 >> 18) * 17 + q * 4;
        atomicAdd(a0 + 0, m0.x); atomicAdd(a0 + 1, m0.y);
        atomicAdd(a0 + 2, m0.z); atomicAdd(a0 + 3, m0.w);
        float* a1 = agg + (r1 >> 18) * 17 + q * 4;
        atomicAdd(a1 + 0, m1.x); atomicAdd(a1 + 1, m1.y);
        atomicAdd(a1 + 2, m1.z); atomicAdd(a1 + 3, m1.w);
        float* a2 = agg + (r2 >> 18) * 17 + q * 4;
        atomicAdd(a2 + 0, m2.x); atomicAdd(a2 + 1, m2.y);
        atomicAdd(a2 + 2, m2.z); atomicAdd(a2 + 3, m2.w);
        float* a3 = agg + (r3 >> 18) * 17 + q * 4;
        atomicAdd(a3 + 0, m3.x); atomicAdd(a3 + 1, m3.y);
        atomicAdd(a3 + 2, m3.z); atomicAdd(a3 + 3, m3.w);
    }
    for (; i < hi; i += 64) {                           // tail
        unsigned int r = rec[i];
        float4 mv = mS4[(r & 0x3FFFF) * 4 + q];
        float* a = agg + (r >> 18) * 17 + q * 4;
        atomicAdd(a + 0, mv.x); atomicAdd(a + 1, mv.y);
        atomicAdd(a + 2, mv.z); atomicAdd(a + 3, mv.w);
    }
    __syncthreads();
    int base = b * G;
    for (int v = threadIdx.x; v < G * HID; v += 256) {  // coalesced line-shared atomics
        int nl = v >> 4, c = v & 15;
        int n = base + nl;
        if (n >= N) break;
        float val = agg[nl * 17 + c];
        if (val != 0.f) atomicAdd(gagg + n * HID + c, val);
    }
}

// ---- epilogue layer1: h = relu((gagg + mS[n]) * dinv[n] + b) ----
__global__ void k_post(const float4* __restrict__ gagg4, const float4* __restrict__ mS4,
                       const float* __restrict__ dinv, const float4* __restrict__ b4,
                       float4* __restrict__ h4, int N) {
    int t = blockIdx.x * blockDim.x + threadIdx.x;
    if (t < N * 4) {
        int n = t >> 2, q = t & 3;
        float dn = dinv[n];
        float4 ag = gagg4[t];
        float4 ms = mS4[t];
        float4 bb = b4[q];
        float4 hv;
        hv.x = relu((ag.x + ms.x) * dn + bb.x);
        hv.y = relu((ag.y + ms.y) * dn + bb.y);
        hv.z = relu((ag.z + ms.z) * dn + bb.z);
        hv.w = relu((ag.w + ms.w) * dn + bb.w);
        h4[t] = hv;
    }
}

// ---- epilogue layer2 + readout ----
__global__ void k_out(const float4* __restrict__ gagg4, const float4* __restrict__ mS4,
                      const float* __restrict__ dinv, const float4* __restrict__ b4,
                      const float* __restrict__ Wl, const float* __restrict__ bl,
                      float* __restrict__ out, int N) {
    __shared__ float hs[64][HID + 1];
    __shared__ float wl[HID * OUTC];
    __shared__ float blv[OUTC];
    if (threadIdx.x < HID * OUTC) wl[threadIdx.x] = Wl[threadIdx.x];
    if (threadIdx.x < OUTC) blv[threadIdx.x] = bl[threadIdx.x];
    int idx = blockIdx.x * 256 + threadIdx.x;          // float4 index
    int n = idx >> 2, q = idx & 3;
    int ln = threadIdx.x >> 2;
    if (n < N) {
        float dn = dinv[n];
        float4 ag = gagg4[idx];
        float4 ms = mS4[idx];
        float4 bb = b4[q];
        hs[ln][q * 4 + 0] = relu((ag.x + ms.x) * dn + bb.x);
        hs[ln][q * 4 + 1] = relu((ag.y + ms.y) * dn + bb.y);
        hs[ln][q * 4 + 2] = relu((ag.z + ms.z) * dn + bb.z);
        hs[ln][q * 4 + 3] = relu((ag.w + ms.w) * dn + bb.w);
    }
    __syncthreads();
    if (n < N) {
        float acc = blv[q];
        const float* hr = hs[ln];
#pragma unroll
        for (int ci = 0; ci < HID; ++ci) acc += hr[ci] * wl[ci * OUTC + q];
        out[n * OUTC + q] = acc;
    }
}

// ---------- launch ----------
static inline size_t alignup(size_t v, size_t a) { return (v + a - 1) & ~(a - 1); }

extern "C" void kernel_launch(void* const* d_in, const int* in_sizes, int n_in,
                              void* d_out, int out_size, void* d_ws, size_t ws_size,
                              hipStream_t stream) {
    const float* x  = (const float*)d_in[0];
    const int* ed   = (const int*)d_in[1];     // int inputs delivered as int32
    const float* W1 = (const float*)d_in[2];
    const float* b1 = (const float*)d_in[3];
    const float* W2 = (const float*)d_in[4];
    const float* b2 = (const float*)d_in[5];
    const float* Wl = (const float*)d_in[6];
    const float* bl = (const float*)d_in[7];
    float* out      = (float*)d_out;

    int N = in_sizes[0];
    int E = in_sizes[1] / 2;
    const int* src = ed;
    const int* dst = ed + E;
    int nb = (N + G - 1) / G;                  // 1563 buckets (<= MAXNB)
    int L = nb * CHUNKS;                       // count cells
    int SB = (L + 1023) / 1024;                // scan blocks

    // workspace (cnt aliases bufA: dead before k_m1 writes it)
    char* w = (char*)d_ws;
    size_t o = 0;
    float* dinv       = (float*)(w + o); o = alignup(o + (size_t)N * 4, 16);
    int* bsum         = (int*)(w + o);   o = alignup(o + (size_t)SB * 4, 16);
    int* bOff         = (int*)(w + o);   o = alignup(o + ((size_t)nb + 1) * 4, 16);
    unsigned int* rec = (unsigned int*)(w + o); o = alignup(o + (size_t)E * 4, 16);
    float* bufA       = (float*)(w + o); o = alignup(o + (size_t)N * HID * 4, 16);
    float* bufB       = (float*)(w + o); o = alignup(o + (size_t)N * HID * 4, 16);
    int* cnt          = (int*)bufA;            // L ints <= N*HID floats
    (void)ws_size;

    int blk = 256;
    int gN16 = (N * HID + blk - 1) / blk;
    int gN4  = (N * 4 + blk - 1) / blk;
    int gNode64 = (N + 63) / 64;

    // counting-sort partition (no global atomics anywhere)
    k_cnt<<<CHUNKS, PBLK, 0, stream>>>(dst, cnt, E, nb);
    k_scanA<<<SB, 1024, 0, stream>>>(cnt, bsum, L);
    k_scanB<<<1, 1024, 0, stream>>>(bsum, SB);
    k_scanC<<<SB, 1024, 0, stream>>>(cnt, bsum, bOff, L, nb, E);
    k_part<<<CHUNKS, PBLK, 0, stream>>>(src, dst, cnt, rec, E, nb);
    k_degb<<<nb, blk, 0, stream>>>(bOff, rec, dinv, N);

    // layer 1
    k_m1<<<gN16, blk, 0, stream>>>(x, W1, dinv, bufA, N);
    hipMemsetAsync(bufB, 0, (size_t)N * HID * 4, stream);
    k_agg<<<nb * SPLIT, blk, 0, stream>>>(bOff, rec, (const float4*)bufA, bufB, N);
    k_post<<<gN4, blk, 0, stream>>>((const float4*)bufB, (const float4*)bufA, dinv,
                                    (const float4*)b1, (float4*)bufA, N);   // bufA = h1

    // layer 2
    k_m2<<<gNode64, blk, 0, stream>>>((float4*)bufA, W2, dinv, N);          // bufA = mS2
    hipMemsetAsync(bufB, 0, (size_t)N * HID * 4, stream);
    k_agg<<<nb * SPLIT, blk, 0, stream>>>(bOff, rec, (const float4*)bufA, bufB, N);
    k_out<<<gNode64, blk, 0, stream>>>((const float4*)bufB, (const float4*)bufA, dinv,
                                       (const float4*)b2, Wl, bl, out, N);
}